// Round 1
// baseline (373.535 us; speedup 1.0000x reference)
//
#include <hip/hip_runtime.h>
#include <math.h>

// ProtoLoss: loss = mean_n( -2*sim[n,fam[n]] + logsumexp_f(4*sim[n,f]) )
// sim = (e.p)/(||e||*||p||) -- scale-invariant in p, so the segment-mean's
// count division cancels: p_hat = raw_sum/||raw_sum||. No counts anywhere.
// N=262144, D=128, F=64.
//
// Layout note: lane l of a pass_a wave owns dims (l, l+64) of its row (keeps
// the LDS f32 atomics on all 32 banks, 2 lanes/bank = free). ehat therefore
// stores bf16 pairs interleaved: uint j of a row = (dim j+64)<<16 | dim j.
// protoB is written with the SAME k-permutation, so pass_c's MFMA dots
// corresponding elements and the sum over K=128 is unchanged.
//
// A) segment raw sums: 256 blocks x 1024 thr (16 waves/CU = 4x old occupancy).
//    4 LDS replicas (128 KB), 4 waves share one replica via ds_add_f32
//    (fire-and-forget, no RMW dependency). Writes e_hat bf16 (67 MB -> L3).
// B1) 256-block reduce of 256 partials -> protoRaw fp32 (unchanged).
// B2) 1-block normalize -> protoB bf16 (interleaved layout) + zero d_out.
// C) de-staged MFMA: A fragments straight from L3-warm ehat, B fragments
//    from L1-resident protoB; no LDS tiles, no pre-loop barrier.

#define D_DIM 128
#define F_NUM 64

typedef __attribute__((ext_vector_type(8))) short short8;
typedef __attribute__((ext_vector_type(4))) float f32x4;

static __device__ __forceinline__ unsigned short f2bf(float x) {
  union { float f; unsigned u; } v; v.f = x;
  unsigned r = v.u + 0x7FFFu + ((v.u >> 16) & 1u);   // RNE
  return (unsigned short)(r >> 16);
}

// ---------------- Pass A -----------------------------------------------------
// grid N/1024 x 1024 thr (16 waves). Wave w -> rows [blk*1024+w*64, +64),
// replica (w&3). Lane l holds dims l and l+64 (two dword loads 256B apart).
// Full-wave shfl reduce -> exact fp32 norm -> e_hat bf16 (interleaved pack).
// 16-row batches keep 8 KB/wave of loads in flight.
__global__ __launch_bounds__(1024) void pass_a(
    const float* __restrict__ emb, const int* __restrict__ fam,
    float* __restrict__ psum, unsigned int* __restrict__ ehat)
{
  __shared__ float acc[4 * F_NUM * D_DIM];   // 128 KB
  int t = threadIdx.x;
  float4 z = make_float4(0.f, 0.f, 0.f, 0.f);
  float4* a4 = (float4*)acc;
  #pragma unroll
  for (int k = 0; k < 8; ++k) a4[t + k * 1024] = z;
  __syncthreads();

  int w = t >> 6, l = t & 63;
  float* my = acc + (w & 3) * (F_NUM * D_DIM); // [64 fams][128 dims], natural order
  int base = __builtin_amdgcn_readfirstlane(blockIdx.x * 1024 + w * 64);

  #pragma unroll 1
  for (int b = 0; b < 4; ++b) {
    float x[16], y[16]; int f[16];
    #pragma unroll
    for (int j = 0; j < 16; ++j) {           // 16 independent rows
      int r = base + b * 16 + j;
      x[j] = emb[(size_t)r * D_DIM + l];
      y[j] = emb[(size_t)r * D_DIM + 64 + l];
      f[j] = fam[r];                         // uniform -> s_load
    }
    #pragma unroll
    for (int j = 0; j < 16; ++j) {
      float nq = x[j] * x[j] + y[j] * y[j];  // full ||e||^2 via 64-lane butterfly
      nq += __shfl_xor(nq, 1);  nq += __shfl_xor(nq, 2);  nq += __shfl_xor(nq, 4);
      nq += __shfl_xor(nq, 8);  nq += __shfl_xor(nq, 16); nq += __shfl_xor(nq, 32);
      float inv = rsqrtf(fmaxf(nq, 1e-20f));
      ehat[(size_t)(base + b * 16 + j) * 64 + l] =
          ((unsigned)f2bf(y[j] * inv) << 16) | f2bf(x[j] * inv);
      // bank-free: addr strides 4B over 64 lanes (banks 0..31 x2)
      atomicAdd(&my[f[j] * D_DIM + l], x[j]);
      atomicAdd(&my[f[j] * D_DIM + 64 + l], y[j]);
    }
  }
  __syncthreads();

  // merge 4 replicas -> block-private psum slot (streaming dwordx4 stores)
  float4* out4 = (float4*)(psum + (size_t)blockIdx.x * (F_NUM * D_DIM));
  #pragma unroll
  for (int k = 0; k < 2; ++k) {
    int idx4 = t + k * 1024;                 // 0..2047 float4s of [f][128]
    float4 r = z;
    #pragma unroll
    for (int rp = 0; rp < 4; ++rp) {
      float4 a = a4[rp * 2048 + idx4];
      r.x += a.x; r.y += a.y; r.z += a.z; r.w += a.w;
    }
    out4[idx4] = r;
  }
}

// ---------------- Pass B1 ----------------------------------------------------
// 256 blocks (f x dim-quarter) x 256 thr: reduce nPart partials -> protoRaw.
__global__ __launch_bounds__(256) void pass_b1(
    const float* __restrict__ psum, float* __restrict__ protoRaw, int nPart)
{
  __shared__ float red[256];
  int f = blockIdx.x >> 2, qd = blockIdx.x & 3;
  int t = threadIdx.x;
  int d = qd * 32 + (t & 31), p0 = t >> 5;   // 8 partial-groups
  int per = nPart >> 3;
  float s = 0.f;
  #pragma unroll 8
  for (int i = 0; i < per; ++i)
    s += psum[(size_t)(p0 + 8 * i) * (F_NUM * D_DIM) + f * D_DIM + d];
  red[t] = s;
  __syncthreads();
  if (t < 32) {
    float r = 0.f;
    #pragma unroll
    for (int k = 0; k < 8; ++k) r += red[k * 32 + t];
    protoRaw[f * D_DIM + qd * 32 + t] = r;
  }
}

// ---------------- Pass B2 ----------------------------------------------------
// 1 block x 256 thr: thread (f=t>>2, pt=t&3) handles output elems [32pt,32pt+32).
// Output layout matches ehat: elem 2j = dim j, elem 2j+1 = dim j+64.
// Also zeroes d_out (runs before pass_c in-stream).
__global__ __launch_bounds__(256) void pass_b2(
    const float* __restrict__ protoRaw, unsigned short* __restrict__ protoB,
    float* __restrict__ out)
{
  int t = threadIdx.x, f = t >> 2, pt = t & 3;
  if (t == 0) out[0] = 0.f;
  const float4* lo4 = (const float4*)(protoRaw + f * D_DIM + pt * 16);
  const float4* hi4 = (const float4*)(protoRaw + f * D_DIM + 64 + pt * 16);
  float lo[16], hi[16];
  float n2 = 0.f;
  #pragma unroll
  for (int i = 0; i < 4; ++i) {
    float4 a = lo4[i], b = hi4[i];
    lo[4 * i + 0] = a.x; lo[4 * i + 1] = a.y; lo[4 * i + 2] = a.z; lo[4 * i + 3] = a.w;
    hi[4 * i + 0] = b.x; hi[4 * i + 1] = b.y; hi[4 * i + 2] = b.z; hi[4 * i + 3] = b.w;
    n2 += a.x * a.x + a.y * a.y + a.z * a.z + a.w * a.w;
    n2 += b.x * b.x + b.y * b.y + b.z * b.z + b.w * b.w;
  }
  n2 += __shfl_xor(n2, 1);                   // quad = same f
  n2 += __shfl_xor(n2, 2);
  float inv = rsqrtf(fmaxf(n2, 1e-24f));     // zero-family -> p_hat=0 -> sim=0
  ushort4* dst = (ushort4*)(protoB + f * D_DIM + pt * 32);
  #pragma unroll
  for (int i = 0; i < 8; ++i) {
    ushort4 u;
    u.x = f2bf(lo[2 * i] * inv);     u.y = f2bf(hi[2 * i] * inv);
    u.z = f2bf(lo[2 * i + 1] * inv); u.w = f2bf(hi[2 * i + 1] * inv);
    dst[i] = u;
  }
}

// ---------------- Pass C -----------------------------------------------------
// N/128 blocks x 256 thr. Tile: 128 rows x 64 fams, K=128, bf16 MFMA 16x16x32.
// No LDS tiles: A rows have zero cross-wave reuse (L3-warm ehat, direct 16B
// loads); B is 16 KB -> L1-resident broadcast. Only barrier is the sWp reduce.
__global__ __launch_bounds__(256) void pass_c(
    const unsigned short* __restrict__ ehat, const int* __restrict__ fam,
    const unsigned short* __restrict__ protoB,
    float* __restrict__ out, float invN)
{
  __shared__ float sWp[4];
  int t = threadIdx.x;
  int R0 = blockIdx.x * 128;
  int w = t >> 6, lane = t & 63, m16 = lane & 15, q = lane >> 4;

  const short8* A16 = (const short8*)ehat;   // 16 chunks of 8 bf16 per row
  const short8* B16 = (const short8*)protoB;

  // hoist fam for this lane's 8 output rows (L1 broadcast across m16)
  int frv[2][4];
  #pragma unroll
  for (int rt = 0; rt < 2; ++rt)
    #pragma unroll
    for (int i = 0; i < 4; ++i)
      frv[rt][i] = fam[R0 + w * 32 + rt * 16 + q * 4 + i];

  // B fragments: fam row ft*16+m16, chunk ks*4+q (k-offset ks*32+q*8)
  short8 bfr[4][4];
  #pragma unroll
  for (int ks = 0; ks < 4; ++ks)
    #pragma unroll
    for (int ft = 0; ft < 4; ++ft)
      bfr[ks][ft] = B16[(ft * 16 + m16) * 16 + ks * 4 + q];

  size_t aBase = (size_t)(R0 + w * 32 + m16) * 16 + q;
  f32x4 acc[2][4] = {};
  #pragma unroll
  for (int ks = 0; ks < 4; ++ks) {
    short8 a0 = A16[aBase + ks * 4];         // row w*32+m16
    short8 a1 = A16[aBase + 256 + ks * 4];   // row +16
    acc[0][0] = __builtin_amdgcn_mfma_f32_16x16x32_bf16(a0, bfr[ks][0], acc[0][0], 0, 0, 0);
    acc[0][1] = __builtin_amdgcn_mfma_f32_16x16x32_bf16(a0, bfr[ks][1], acc[0][1], 0, 0, 0);
    acc[0][2] = __builtin_amdgcn_mfma_f32_16x16x32_bf16(a0, bfr[ks][2], acc[0][2], 0, 0, 0);
    acc[0][3] = __builtin_amdgcn_mfma_f32_16x16x32_bf16(a0, bfr[ks][3], acc[0][3], 0, 0, 0);
    acc[1][0] = __builtin_amdgcn_mfma_f32_16x16x32_bf16(a1, bfr[ks][0], acc[1][0], 0, 0, 0);
    acc[1][1] = __builtin_amdgcn_mfma_f32_16x16x32_bf16(a1, bfr[ks][1], acc[1][1], 0, 0, 0);
    acc[1][2] = __builtin_amdgcn_mfma_f32_16x16x32_bf16(a1, bfr[ks][2], acc[1][2], 0, 0, 0);
    acc[1][3] = __builtin_amdgcn_mfma_f32_16x16x32_bf16(a1, bfr[ks][3], acc[1][3], 0, 0, 0);
  }

  // epilogue: sim = acc (normalized operands).
  // D[row= w*32+rt*16+q*4+i][col= ft*16+m16] = acc[rt][ft][i]
  float wp = 0.f;
  #pragma unroll
  for (int rt = 0; rt < 2; ++rt) {
    #pragma unroll
    for (int i = 0; i < 4; ++i) {
      int fr = frv[rt][i], frh = fr >> 4, frl = fr & 15;
      float es = 0.f, ps = 0.f;
      #pragma unroll
      for (int ft = 0; ft < 4; ++ft) {
        float sim = acc[rt][ft][i];
        es += __expf(4.f * sim - 4.f);       // sim in [-1,1] -> arg in [-8,0]
        if (frl == m16 && frh == ft) ps = sim;
      }
      #pragma unroll
      for (int off = 1; off < 16; off <<= 1) {
        es += __shfl_xor(es, off);
        ps += __shfl_xor(ps, off);
      }
      if (m16 == 0) wp += 4.f + __logf(es) - 2.f * ps;
    }
  }
  wp += __shfl_xor(wp, 16);
  wp += __shfl_xor(wp, 32);
  if (lane == 0) sWp[w] = wp;
  __syncthreads();
  if (t == 0)
    unsafeAtomicAdd(out, (sWp[0] + sWp[1] + sWp[2] + sWp[3]) * invN);
}

extern "C" void kernel_launch(void* const* d_in, const int* in_sizes, int n_in,
                              void* d_out, int out_size, void* d_ws, size_t ws_size,
                              hipStream_t stream) {
  const float* emb = (const float*)d_in[0];
  const int* fam = (const int*)d_in[1];
  int N = in_sizes[0] / D_DIM;               // 262144
  int blocksA = N / 1024;                    // 256
  int blocksC = N / 128;                     // 2048

  // ws (float units): psum[256*8192] | protoRaw[8192] | protoB(8192 ushort)
  // | ehat[N*64 uint]
  float* ws = (float*)d_ws;
  float* psum = ws;
  size_t off = (size_t)blocksA * (F_NUM * D_DIM);
  float* protoRaw = ws + off;                off += F_NUM * D_DIM;
  unsigned short* protoB = (unsigned short*)(ws + off); off += (F_NUM * D_DIM) / 2;
  unsigned int* ehat = (unsigned int*)(ws + off);

  pass_a<<<blocksA, 1024, 0, stream>>>(emb, fam, psum, ehat);
  pass_b1<<<4 * F_NUM, 256, 0, stream>>>(psum, protoRaw, blocksA);
  pass_b2<<<1, 256, 0, stream>>>(protoRaw, protoB, (float*)d_out);
  pass_c<<<blocksC, 256, 0, stream>>>((const unsigned short*)ehat, fam, protoB,
                                      (float*)d_out, 1.0f / (float)N);
}